// Round 1
// baseline (1060.609 us; speedup 1.0000x reference)
//
#include <hip/hip_runtime.h>
#include <hip/hip_bf16.h>
#include <math.h>

#define NPT 2048
#define BB 4
#define KNN 20
#define M3 (3*NPT)       // 6144 columns per (b) for flattened (vec,n)
#define EPSV 1e-6f

// ---------------------------------------------------------------- kNN top-20
__global__ __launch_bounds__(256)
void knn_kernel(const float* __restrict__ p, int* __restrict__ idx) {
    int bn = blockIdx.x;
    int b = bn >> 11, n = bn & (NPT - 1);
    const float* pb = p + (size_t)b * NPT * 3;
    float qx = pb[n*3+0], qy = pb[n*3+1], qz = pb[n*3+2];
    float qq = qx*qx + qy*qy + qz*qz;
    __shared__ float sc[NPT];
    __shared__ float rv[256];
    __shared__ int   ri[256];
    int tid = threadIdx.x;
    for (int m = tid; m < NPT; m += 256) {
        float px = pb[m*3+0], py = pb[m*3+1], pz = pb[m*3+2];
        float pp = px*px + py*py + pz*pz;
        sc[m] = 2.f*(qx*px + qy*py + qz*pz) - qq - pp;
    }
    __syncthreads();
    for (int kk = 0; kk < KNN; ++kk) {
        float best = -INFINITY; int bi = NPT;
        for (int m = tid; m < NPT; m += 256) {
            float v = sc[m];
            if (v > best) { best = v; bi = m; }   // first hit keeps smallest m
        }
        rv[tid] = best; ri[tid] = bi;
        __syncthreads();
        for (int s = 128; s > 0; s >>= 1) {
            if (tid < s) {
                float v2 = rv[tid+s]; int i2 = ri[tid+s];
                if (v2 > rv[tid] || (v2 == rv[tid] && i2 < ri[tid])) { rv[tid] = v2; ri[tid] = i2; }
            }
            __syncthreads();
        }
        if (tid == 0) { idx[(size_t)bn*KNN + kk] = ri[0]; sc[ri[0]] = -INFINITY; }
        __syncthreads();
    }
}

// ------------------------------------------- edge conv + leaky(0.2) + mean_k
__global__ __launch_bounds__(128)
void edgeconv_kernel(const float* __restrict__ p, const int* __restrict__ idx,
                     const float* __restrict__ wf, const float* __restrict__ wd,
                     float* __restrict__ net1) {
    int bn = blockIdx.x;
    int b = bn >> 11, n = bn & (NPT - 1);
    __shared__ float nb[KNN][3];
    __shared__ float ctr[3];
    int tid = threadIdx.x;
    if (tid < KNN) {
        int j = idx[(size_t)bn*KNN + tid];
        const float* pj = p + ((size_t)b*NPT + j)*3;
        nb[tid][0] = pj[0]; nb[tid][1] = pj[1]; nb[tid][2] = pj[2];
    }
    if (tid >= 64 && tid < 67) ctr[tid-64] = p[((size_t)b*NPT + n)*3 + (tid-64)];
    __syncthreads();
    int o = tid;
    float wfa = wf[o*3+0], wfb = wf[o*3+1], wfc = wf[o*3+2];
    float wda = wd[o*3+0], wdb = wd[o*3+1], wdc = wd[o*3+2];
    float cx = ctr[0], cy = ctr[1], cz = ctr[2];
    float a0 = 0.f, a1 = 0.f, a2 = 0.f;
    #pragma unroll 4
    for (int k = 0; k < KNN; ++k) {
        float nx = nb[k][0], ny = nb[k][1], nz = nb[k][2];
        float rx = nx-cx, ry = ny-cy, rz = nz-cz;
        float sx = ny*cz - nz*cy;
        float sy = nz*cx - nx*cz;
        float sz = nx*cy - ny*cx;
        float fx = wfa*rx + wfb*cx + wfc*sx;
        float fy = wfa*ry + wfb*cy + wfc*sy;
        float fz = wfa*rz + wfb*cz + wfc*sz;
        float dx0 = wda*rx + wdb*cx + wdc*sx;
        float dy0 = wda*ry + wdb*cy + wdc*sy;
        float dz0 = wda*rz + wdb*cz + wdc*sz;
        float dot = fx*dx0 + fy*dy0 + fz*dz0;
        float dsq = dx0*dx0 + dy0*dy0 + dz0*dz0;
        float t = dot / (dsq + EPSV);
        bool pos = dot >= 0.f;
        float gx = pos ? fx : (fx - t*dx0);
        float gy = pos ? fy : (fy - t*dy0);
        float gz = pos ? fz : (fz - t*dz0);
        a0 += 0.2f*fx + 0.8f*gx;
        a1 += 0.2f*fy + 0.8f*gy;
        a2 += 0.2f*fz + 0.8f*gz;
    }
    const float s = 1.f / (float)KNN;
    float* dst = net1 + ((size_t)(b*128 + o)*3)*NPT + n;
    dst[0]       = a0*s;
    dst[NPT]     = a1*s;
    dst[2*NPT]   = a2*s;
}

// ------------------------------------------------------- plain VN GEMM (+skip)
// Y[b,o,m] = sum_c W1[o,c] X1[b,c,m]  (+ sum_c W2[o,c] X2[b,c,m])
// grid: (M3/128, O/32, B), block 256. Each thread: 8 o x 2 cols.
template<int O, int C1, int C2>
__global__ __launch_bounds__(256)
void vn_gemm(const float* __restrict__ W1, const float* __restrict__ X1,
             const float* __restrict__ W2, const float* __restrict__ X2,
             float* __restrict__ Y) {
    int b = blockIdx.z;
    int m = blockIdx.x * 128 + (int)(threadIdx.x & 63);
    int wvid = __builtin_amdgcn_readfirstlane((int)(threadIdx.x >> 6));
    int oBase = blockIdx.y * 32 + wvid * 8;
    const float* x1 = X1 + (size_t)b*C1*M3 + m;
    float acc0[8] = {}, acc1[8] = {};
    {
        const float* w = W1 + (size_t)oBase*C1;
        #pragma unroll 4
        for (int c = 0; c < C1; ++c) {
            float xa = x1[(size_t)c*M3];
            float xb = x1[(size_t)c*M3 + 64];
            #pragma unroll
            for (int i = 0; i < 8; ++i) {
                float wv = w[i*C1 + c];
                acc0[i] += wv*xa; acc1[i] += wv*xb;
            }
        }
    }
    if constexpr (C2 > 0) {
        const float* x2 = X2 + (size_t)b*C2*M3 + m;
        const float* w = W2 + (size_t)oBase*C2;
        #pragma unroll 4
        for (int c = 0; c < C2; ++c) {
            float xa = x2[(size_t)c*M3];
            float xb = x2[(size_t)c*M3 + 64];
            #pragma unroll
            for (int i = 0; i < 8; ++i) {
                float wv = w[i*C2 + c];
                acc0[i] += wv*xa; acc1[i] += wv*xb;
            }
        }
    }
    float* y = Y + ((size_t)b*O + oBase)*M3 + m;
    #pragma unroll
    for (int i = 0; i < 8; ++i) {
        y[(size_t)i*M3]      = acc0[i];
        y[(size_t)i*M3 + 64] = acc1[i];
    }
}

// ---------------------------------------- dir GEMM (OxC, O==C) + fused VN-leaky
// d = Wd X ; A = leaky(X, d, slope). grid: (N/64, C/32, B), block 256.
template<int C>
__global__ __launch_bounds__(256)
void vn_dir_leaky(const float* __restrict__ Wd, const float* __restrict__ X,
                  float* __restrict__ A, float slope) {
    int b = blockIdx.z;
    int n = blockIdx.x * 64 + (int)(threadIdx.x & 63);
    int wvid = __builtin_amdgcn_readfirstlane((int)(threadIdx.x >> 6));
    int oBase = blockIdx.y * 32 + wvid * 8;
    const float* xb = X + (size_t)b*C*M3 + n;
    float d0[8] = {}, d1[8] = {}, d2[8] = {};
    const float* w = Wd + (size_t)oBase*C;
    #pragma unroll 4
    for (int c = 0; c < C; ++c) {
        float xa = xb[(size_t)c*M3];
        float xv = xb[(size_t)c*M3 + NPT];
        float xc = xb[(size_t)c*M3 + 2*NPT];
        #pragma unroll
        for (int i = 0; i < 8; ++i) {
            float wv = w[i*C + c];
            d0[i] += wv*xa; d1[i] += wv*xv; d2[i] += wv*xc;
        }
    }
    #pragma unroll
    for (int i = 0; i < 8; ++i) {
        const float* xr = xb + (size_t)(oBase + i)*M3;
        float x0 = xr[0], x1 = xr[NPT], x2 = xr[2*NPT];
        float dot = d0[i]*x0 + d1[i]*x1 + d2[i]*x2;
        float dsq = d0[i]*d0[i] + d1[i]*d1[i] + d2[i]*d2[i];
        float t = dot / (dsq + EPSV);
        bool pos = dot >= 0.f;
        float g0 = pos ? x0 : (x0 - t*d0[i]);
        float g1 = pos ? x1 : (x1 - t*d1[i]);
        float g2 = pos ? x2 : (x2 - t*d2[i]);
        float y0 = slope*x0 + (1.f - slope)*g0;
        float y1 = slope*x1 + (1.f - slope)*g1;
        float y2 = slope*x2 + (1.f - slope)*g2;
        float* ar = A + (size_t)b*C*M3 + (size_t)(oBase + i)*M3 + n;
        ar[0] = y0; ar[NPT] = y1; ar[2*NPT] = y2;
    }
}

// -------------------------------------- pool over n + build concat input X
// X[b, c,      :, :] = Y[b, c, :, :]
// X[b, c+128,  :, :] = mean_n Y[b, c, :, :]
__global__ __launch_bounds__(256)
void pool_concat_kernel(const float* __restrict__ Y, float* __restrict__ X) {
    int b = blockIdx.x >> 7;
    int c = blockIdx.x & 127;
    const float* yr = Y + ((size_t)b*128 + c)*M3;
    int tid = threadIdx.x;
    float s0 = 0.f, s1 = 0.f, s2 = 0.f;
    for (int n = tid; n < NPT; n += 256) { s0 += yr[n]; s1 += yr[NPT+n]; s2 += yr[2*NPT+n]; }
    __shared__ float red[3][256];
    red[0][tid] = s0; red[1][tid] = s1; red[2][tid] = s2;
    __syncthreads();
    for (int s = 128; s > 0; s >>= 1) {
        if (tid < s) {
            red[0][tid] += red[0][tid+s];
            red[1][tid] += red[1][tid+s];
            red[2][tid] += red[2][tid+s];
        }
        __syncthreads();
    }
    float m0 = red[0][0]*(1.f/NPT), m1 = red[1][0]*(1.f/NPT), m2 = red[2][0]*(1.f/NPT);
    float* xlo = X + ((size_t)b*256 + c)*M3;
    float* xhi = X + ((size_t)b*256 + 128 + c)*M3;
    for (int n = tid; n < NPT; n += 256) {
        xlo[n] = yr[n]; xlo[NPT+n] = yr[NPT+n]; xlo[2*NPT+n] = yr[2*NPT+n];
        xhi[n] = m0;    xhi[NPT+n] = m1;        xhi[2*NPT+n] = m2;
    }
}

// ------------------------------------------------ final mean pool -> q[B,128,3]
__global__ __launch_bounds__(256)
void pool_final_kernel(const float* __restrict__ Y, float* __restrict__ q) {
    int b = blockIdx.x >> 7;
    int c = blockIdx.x & 127;
    const float* yr = Y + ((size_t)b*128 + c)*M3;
    int tid = threadIdx.x;
    float s0 = 0.f, s1 = 0.f, s2 = 0.f;
    for (int n = tid; n < NPT; n += 256) { s0 += yr[n]; s1 += yr[NPT+n]; s2 += yr[2*NPT+n]; }
    __shared__ float red[3][256];
    red[0][tid] = s0; red[1][tid] = s1; red[2][tid] = s2;
    __syncthreads();
    for (int s = 128; s > 0; s >>= 1) {
        if (tid < s) {
            red[0][tid] += red[0][tid+s];
            red[1][tid] += red[1][tid+s];
            red[2][tid] += red[2][tid+s];
        }
        __syncthreads();
    }
    if (tid == 0) {
        q[((size_t)b*128 + c)*3 + 0] = red[0][0]*(1.f/NPT);
        q[((size_t)b*128 + c)*3 + 1] = red[1][0]*(1.f/NPT);
        q[((size_t)b*128 + c)*3 + 2] = red[2][0]*(1.f/NPT);
    }
}

// ----------------------------------------------------- head: leaky(0.2) + fc_c
__global__ __launch_bounds__(128)
void final_head_kernel(const float* __restrict__ q, const float* __restrict__ Wdir,
                       const float* __restrict__ Wfc, float* __restrict__ out) {
    int b = blockIdx.x; int o = threadIdx.x;
    __shared__ float qs[128][3];
    __shared__ float zs[128][3];
    qs[o][0] = q[((size_t)b*128 + o)*3 + 0];
    qs[o][1] = q[((size_t)b*128 + o)*3 + 1];
    qs[o][2] = q[((size_t)b*128 + o)*3 + 2];
    __syncthreads();
    float d0 = 0.f, d1 = 0.f, d2 = 0.f;
    for (int c = 0; c < 128; ++c) {
        float w = Wdir[o*128 + c];
        d0 += w*qs[c][0]; d1 += w*qs[c][1]; d2 += w*qs[c][2];
    }
    float x0 = qs[o][0], x1 = qs[o][1], x2 = qs[o][2];
    float dot = d0*x0 + d1*x1 + d2*x2;
    float dsq = d0*d0 + d1*d1 + d2*d2;
    float t = dot / (dsq + EPSV);
    bool pos = dot >= 0.f;
    float g0 = pos ? x0 : (x0 - t*d0);
    float g1 = pos ? x1 : (x1 - t*d1);
    float g2 = pos ? x2 : (x2 - t*d2);
    zs[o][0] = 0.2f*x0 + 0.8f*g0;
    zs[o][1] = 0.2f*x1 + 0.8f*g1;
    zs[o][2] = 0.2f*x2 + 0.8f*g2;
    __syncthreads();
    float c0 = 0.f, c1 = 0.f, c2 = 0.f;
    for (int c = 0; c < 128; ++c) {
        float w = Wfc[o*128 + c];
        c0 += w*zs[c][0]; c1 += w*zs[c][1]; c2 += w*zs[c][2];
    }
    out[((size_t)b*128 + o)*3 + 0] = c0;
    out[((size_t)b*128 + o)*3 + 1] = c1;
    out[((size_t)b*128 + o)*3 + 2] = c2;
}

extern "C" void kernel_launch(void* const* d_in, const int* in_sizes, int n_in,
                              void* d_out, int out_size, void* d_ws, size_t ws_size,
                              hipStream_t stream) {
    const float* p           = (const float*)d_in[0];
    const float* w_conv_feat = (const float*)d_in[1];
    const float* w_conv_dir  = (const float*)d_in[2];
    const float* w_fc_pos    = (const float*)d_in[3];
    const float* blk_dir0    = (const float*)d_in[4];
    const float* blk_fc0     = (const float*)d_in[5];
    const float* blk_dir1    = (const float*)d_in[6];
    const float* blk_fc1     = (const float*)d_in[7];
    const float* blk_sc      = (const float*)d_in[8];
    const float* w_actc_dir  = (const float*)d_in[9];
    const float* w_fc_c      = (const float*)d_in[10];
    float* out = (float*)d_out;

    float* ws = (float*)d_ws;
    int* idx = (int*)d_ws;
    size_t off = (size_t)BB*NPT*KNN;                    // idx ints
    float* net1 = ws + off; off += (size_t)BB*128*3*NPT;
    float* X    = ws + off; off += (size_t)BB*256*3*NPT;
    float* A    = ws + off; off += (size_t)BB*256*3*NPT;
    float* T    = ws + off; off += (size_t)BB*128*3*NPT;
    float* Y    = ws + off; off += (size_t)BB*128*3*NPT;
    float* q    = ws + off; off += (size_t)BB*128*3;
    float* U    = A;  // reuse: A is dead once T is produced

    knn_kernel<<<BB*NPT, 256, 0, stream>>>(p, idx);
    edgeconv_kernel<<<BB*NPT, 128, 0, stream>>>(p, idx, w_conv_feat, w_conv_dir, net1);
    vn_gemm<256,128,0><<<dim3(M3/128, 256/32, BB), 256, 0, stream>>>(w_fc_pos, net1, nullptr, nullptr, X);

    for (int i = 0; i < 5; ++i) {
        vn_dir_leaky<256><<<dim3(NPT/64, 256/32, BB), 256, 0, stream>>>(blk_dir0 + (size_t)i*256*256, X, A, 0.f);
        vn_gemm<128,256,0><<<dim3(M3/128, 128/32, BB), 256, 0, stream>>>(blk_fc0 + (size_t)i*128*256, A, nullptr, nullptr, T);
        vn_dir_leaky<128><<<dim3(NPT/64, 128/32, BB), 256, 0, stream>>>(blk_dir1 + (size_t)i*128*128, T, U, 0.f);
        vn_gemm<128,128,256><<<dim3(M3/128, 128/32, BB), 256, 0, stream>>>(blk_fc1 + (size_t)i*128*128, U, blk_sc + (size_t)i*128*256, X, Y);
        if (i < 4) pool_concat_kernel<<<BB*128, 256, 0, stream>>>(Y, X);
    }

    pool_final_kernel<<<BB*128, 256, 0, stream>>>(Y, q);
    final_head_kernel<<<BB, 128, 0, stream>>>(q, w_actc_dir, w_fc_c, out);
}

// Round 2
// 575.315 us; speedup vs baseline: 1.8435x; 1.8435x over previous
//
#include <hip/hip_runtime.h>
#include <math.h>

#define NPT 2048
#define BB 4
#define KNN 20
#define EPSV 1e-6f

typedef unsigned short u16;
typedef unsigned int u32;
typedef __attribute__((ext_vector_type(8))) short short8;
typedef __attribute__((ext_vector_type(4))) float f32x4;
typedef __attribute__((ext_vector_type(4))) u32 uint4v;

#define MFMA16(a,b,c) __builtin_amdgcn_mfma_f32_16x16x32_bf16((a),(b),(c),0,0,0)

__device__ __forceinline__ u16 f2bh(float f) {
    u32 u = __builtin_bit_cast(u32, f);
    return (u16)((u + 0x7FFFu + ((u >> 16) & 1u)) >> 16);
}
__device__ __forceinline__ float bh2f(u32 hbits) {
    return __builtin_bit_cast(float, hbits << 16);
}

// ---------------------------------------------------------------- kNN top-20
__global__ __launch_bounds__(256)
void knn_kernel(const float* __restrict__ p, int* __restrict__ idx) {
    int bn = blockIdx.x;
    int b = bn >> 11, n = bn & (NPT - 1);
    const float* pb = p + (size_t)b * NPT * 3;
    float qx = pb[n*3+0], qy = pb[n*3+1], qz = pb[n*3+2];
    float qq = qx*qx + qy*qy + qz*qz;
    __shared__ float sc[NPT];
    __shared__ float rv[256];
    __shared__ int   ri[256];
    int tid = threadIdx.x;
    for (int m = tid; m < NPT; m += 256) {
        float px = pb[m*3+0], py = pb[m*3+1], pz = pb[m*3+2];
        float pp = px*px + py*py + pz*pz;
        sc[m] = 2.f*(qx*px + qy*py + qz*pz) - qq - pp;
    }
    __syncthreads();
    for (int kk = 0; kk < KNN; ++kk) {
        float best = -INFINITY; int bi = NPT;
        for (int m = tid; m < NPT; m += 256) {
            float v = sc[m];
            if (v > best) { best = v; bi = m; }
        }
        rv[tid] = best; ri[tid] = bi;
        __syncthreads();
        for (int s = 128; s > 0; s >>= 1) {
            if (tid < s) {
                float v2 = rv[tid+s]; int i2 = ri[tid+s];
                if (v2 > rv[tid] || (v2 == rv[tid] && i2 < ri[tid])) { rv[tid] = v2; ri[tid] = i2; }
            }
            __syncthreads();
        }
        if (tid == 0) { idx[(size_t)bn*KNN + kk] = ri[0]; sc[ri[0]] = -INFINITY; }
        __syncthreads();
    }
}

// ---------------------- edge conv + leaky(0.2) + mean_k -> split-bf16 K-major
__global__ __launch_bounds__(128)
void edgeconv_kernel(const float* __restrict__ p, const int* __restrict__ idx,
                     const float* __restrict__ wf, const float* __restrict__ wd,
                     u16* __restrict__ net1h, u16* __restrict__ net1l) {
    int bn = blockIdx.x;
    int b = bn >> 11, n = bn & (NPT - 1);
    __shared__ float nb[KNN][3];
    __shared__ float ctr[3];
    int tid = threadIdx.x;
    if (tid < KNN) {
        int j = idx[(size_t)bn*KNN + tid];
        const float* pj = p + ((size_t)b*NPT + j)*3;
        nb[tid][0] = pj[0]; nb[tid][1] = pj[1]; nb[tid][2] = pj[2];
    }
    if (tid >= 64 && tid < 67) ctr[tid-64] = p[((size_t)b*NPT + n)*3 + (tid-64)];
    __syncthreads();
    int o = tid;
    float wfa = wf[o*3+0], wfb = wf[o*3+1], wfc = wf[o*3+2];
    float wda = wd[o*3+0], wdb = wd[o*3+1], wdc = wd[o*3+2];
    float cx = ctr[0], cy = ctr[1], cz = ctr[2];
    float a0 = 0.f, a1 = 0.f, a2 = 0.f;
    #pragma unroll 4
    for (int k = 0; k < KNN; ++k) {
        float nx = nb[k][0], ny = nb[k][1], nz = nb[k][2];
        float rx = nx-cx, ry = ny-cy, rz = nz-cz;
        float sx = ny*cz - nz*cy;
        float sy = nz*cx - nx*cz;
        float sz = nx*cy - ny*cx;
        float fx = wfa*rx + wfb*cx + wfc*sx;
        float fy = wfa*ry + wfb*cy + wfc*sy;
        float fz = wfa*rz + wfb*cz + wfc*sz;
        float dx0 = wda*rx + wdb*cx + wdc*sx;
        float dy0 = wda*ry + wdb*cy + wdc*sy;
        float dz0 = wda*rz + wdb*cz + wdc*sz;
        float dot = fx*dx0 + fy*dy0 + fz*dz0;
        float dsq = dx0*dx0 + dy0*dy0 + dz0*dz0;
        float t = dot / (dsq + EPSV);
        bool pos = dot >= 0.f;
        float gx = pos ? fx : (fx - t*dx0);
        float gy = pos ? fy : (fy - t*dy0);
        float gz = pos ? fz : (fz - t*dz0);
        a0 += 0.2f*fx + 0.8f*gx;
        a1 += 0.2f*fy + 0.8f*gy;
        a2 += 0.2f*fz + 0.8f*gz;
    }
    const float s = 1.f / (float)KNN;
    float av[3] = {a0*s, a1*s, a2*s};
    #pragma unroll
    for (int v = 0; v < 3; ++v) {
        u16 h = f2bh(av[v]);
        u16 l = f2bh(av[v] - bh2f(h));
        size_t off = (size_t)(b*6144 + v*2048 + n)*128 + o;
        net1h[off] = h; net1l[off] = l;
    }
}

// ------------------------------------------------------ MFMA split-bf16 GEMM
// Y[o, m] = W1*X1 (+ W2*X2) (+ biasS per (b,o,vec)); optional fused pool.
// Activations K-major: X[m][c], m = b*6144 + vec*2048 + n. Block: 128o x 128m.
template<int O, int C1, int C2, bool POOL, bool BIASED>
__global__ __launch_bounds__(256) void gemm_plain(
    const u16* __restrict__ W1h, const u16* __restrict__ W1l, int ldw1,
    const u16* __restrict__ X1h, const u16* __restrict__ X1l, int sx1,
    const u16* __restrict__ W2h, const u16* __restrict__ W2l, int ldw2,
    const u16* __restrict__ X2h, const u16* __restrict__ X2l, int sx2,
    const float* __restrict__ biasS,
    u16* __restrict__ Yh, u16* __restrict__ Yl, int sy,
    float* __restrict__ Pacc)
{
    __shared__ __align__(16) char smem[128*132*4];
    const int m0 = blockIdx.x * 128;
    const int ob = blockIdx.y * 128;
    const int b   = m0 / 6144;
    const int vec = (m0 % 6144) / 2048;
    const int tid = threadIdx.x;
    const int lane = tid & 63;
    const int wid = __builtin_amdgcn_readfirstlane(tid >> 6);
    const int wr = wid & 1, wc = wid >> 1;
    const int l15 = lane & 15, l4 = lane >> 4;

    f32x4 acc[4][4];
    if (BIASED) {
        #pragma unroll
        for (int io = 0; io < 4; ++io) {
            float bv[4];
            #pragma unroll
            for (int r = 0; r < 4; ++r) {
                int o = wr*64 + io*16 + l4*4 + r;
                bv[r] = biasS[(size_t)(b*128 + o)*3 + vec];
            }
            #pragma unroll
            for (int jc = 0; jc < 4; ++jc)
                #pragma unroll
                for (int r = 0; r < 4; ++r) acc[io][jc][r] = bv[r];
        }
    } else {
        #pragma unroll
        for (int io = 0; io < 4; ++io)
            #pragma unroll
            for (int jc = 0; jc < 4; ++jc)
                acc[io][jc] = (f32x4){0.f, 0.f, 0.f, 0.f};
    }

    constexpr int NS = C1/32 + C2/32;
    for (int st = 0; st < NS; ++st) {
        __syncthreads();
        {
            const bool ph2 = (st >= C1/32);
            const u16 *wh, *wl, *xh, *xl; int ldw, sx, cc;
            if (!ph2) { wh=W1h; wl=W1l; xh=X1h; xl=X1l; ldw=ldw1; sx=sx1; cc=st*32; }
            else      { wh=W2h; wl=W2l; xh=X2h; xl=X2l; ldw=ldw2; sx=sx2; cc=(st-C1/32)*32; }
            #pragma unroll
            for (int j = 0; j < 8; ++j) {
                int u = tid + 256*j;
                int pl = u >> 9;
                int id = u & 511;
                int row = id >> 2, q = id & 3;
                const u16* src;
                if (pl == 0)      src = wh + (size_t)(ob + row)*ldw + cc + q*8;
                else if (pl == 1) src = wl + (size_t)(ob + row)*ldw + cc + q*8;
                else if (pl == 2) src = xh + (size_t)(m0 + row)*sx + cc + q*8;
                else              src = xl + (size_t)(m0 + row)*sx + cc + q*8;
                *reinterpret_cast<uint4v*>(smem + pl*10240 + row*80 + q*16) =
                    *reinterpret_cast<const uint4v*>(src);
            }
        }
        __syncthreads();
        short8 fAh[4], fAl[4], fBh[4], fBl[4];
        #pragma unroll
        for (int i = 0; i < 4; ++i) {
            int ra = wr*64 + i*16 + l15;
            fAh[i] = *reinterpret_cast<const short8*>(smem +     0 + ra*80 + l4*16);
            fAl[i] = *reinterpret_cast<const short8*>(smem + 10240 + ra*80 + l4*16);
            int rb = wc*64 + i*16 + l15;
            fBh[i] = *reinterpret_cast<const short8*>(smem + 20480 + rb*80 + l4*16);
            fBl[i] = *reinterpret_cast<const short8*>(smem + 30720 + rb*80 + l4*16);
        }
        #pragma unroll
        for (int io = 0; io < 4; ++io)
            #pragma unroll
            for (int jc = 0; jc < 4; ++jc) {
                acc[io][jc] = MFMA16(fAl[io], fBh[jc], acc[io][jc]);
                acc[io][jc] = MFMA16(fAh[io], fBl[jc], acc[io][jc]);
                acc[io][jc] = MFMA16(fAh[io], fBh[jc], acc[io][jc]);
            }
    }

    __syncthreads();
    float* sd = (float*)smem;
    #pragma unroll
    for (int io = 0; io < 4; ++io)
        #pragma unroll
        for (int jc = 0; jc < 4; ++jc) {
            int jj = wc*64 + jc*16 + l15;
            int orow = wr*64 + io*16 + l4*4;
            *reinterpret_cast<f32x4*>(sd + jj*132 + orow) = acc[io][jc];
        }
    __syncthreads();

    #pragma unroll
    for (int rep = 0; rep < 8; ++rep) {
        int task = tid + 256*rep;
        int oc = task & 15, ml = task >> 4;
        const float* dp = sd + ml*132 + oc*8;
        u32 hw[4], lw[4];
        #pragma unroll
        for (int e2 = 0; e2 < 4; ++e2) {
            float y0 = dp[2*e2], y1 = dp[2*e2+1];
            u16 h0 = f2bh(y0), h1 = f2bh(y1);
            u16 q0 = f2bh(y0 - bh2f(h0)), q1 = f2bh(y1 - bh2f(h1));
            hw[e2] = (u32)h0 | ((u32)h1 << 16);
            lw[e2] = (u32)q0 | ((u32)q1 << 16);
        }
        size_t ooff = (size_t)(m0 + ml)*sy + ob + oc*8;
        *reinterpret_cast<uint4v*>(Yh + ooff) = (uint4v){hw[0],hw[1],hw[2],hw[3]};
        *reinterpret_cast<uint4v*>(Yl + ooff) = (uint4v){lw[0],lw[1],lw[2],lw[3]};
    }

    if (POOL) {
        int o_l = tid & 127, half = tid >> 7;
        float sum = 0.f;
        #pragma unroll 8
        for (int c = 0; c < 64; ++c) sum += sd[(half*64 + c)*132 + o_l];
        atomicAdd(&Pacc[(size_t)(b*128 + o_l)*3 + vec], sum);
    }
}

// ------------------- MFMA split-bf16 dir GEMM + fused VN-leaky(0) epilogue
// Block: 128o x 96cols (3 vec strips x 32 n). VIRT: concat-half via bias + Pm.
template<int O, int CIN, bool VIRT>
__global__ __launch_bounds__(256) void gemm_dir(
    const u16* __restrict__ Wh_, const u16* __restrict__ Wl_, int ldw,
    const u16* __restrict__ X1h, const u16* __restrict__ X1l, int sx,
    const float* __restrict__ biasD, const float* __restrict__ Pm,
    u16* __restrict__ Oh, u16* __restrict__ Ol, int so)
{
    __shared__ __align__(16) char smem[96*132*4];
    const int gx = blockIdx.x;
    const int b  = gx >> 6;
    const int n0 = (gx & 63) * 32;
    const int ob = blockIdx.y * 128;
    const int tid = threadIdx.x;
    const int lane = tid & 63;
    const int wid = __builtin_amdgcn_readfirstlane(tid >> 6);
    const int wr = wid & 1, wc = wid >> 1;
    const int l15 = lane & 15, l4 = lane >> 4;

    f32x4 acc[4][3];
    if (VIRT) {
        #pragma unroll
        for (int io = 0; io < 4; ++io)
            #pragma unroll
            for (int jc = 0; jc < 3; ++jc) {
                int v = (wc*48 + jc*16) >> 5;
                #pragma unroll
                for (int r = 0; r < 4; ++r) {
                    int o = ob + wr*64 + io*16 + l4*4 + r;
                    acc[io][jc][r] = biasD[(size_t)(b*256 + o)*3 + v];
                }
            }
    } else {
        #pragma unroll
        for (int io = 0; io < 4; ++io)
            #pragma unroll
            for (int jc = 0; jc < 3; ++jc)
                acc[io][jc] = (f32x4){0.f, 0.f, 0.f, 0.f};
    }

    for (int st = 0; st < CIN/32; ++st) {
        int cc = st*32;
        __syncthreads();
        #pragma unroll
        for (int j = 0; j < 7; ++j) {
            int u = tid + 256*j;
            const u16* src; char* dst;
            if (u < 1024) {
                int pl = u >> 9; int id = u & 511;
                int row = id >> 2, q = id & 3;
                src = (pl ? Wl_ : Wh_) + (size_t)(ob + row)*ldw + cc + q*8;
                dst = smem + pl*10240 + row*80 + q*16;
            } else {
                int uu = u - 1024;
                int pl = (uu >= 384) ? 1 : 0;
                int id = pl ? uu - 384 : uu;
                int row = id >> 2, q = id & 3;
                int m = b*6144 + (row >> 5)*2048 + n0 + (row & 31);
                src = (pl ? X1l : X1h) + (size_t)m*sx + cc + q*8;
                dst = smem + 20480 + pl*7680 + row*80 + q*16;
            }
            *reinterpret_cast<uint4v*>(dst) = *reinterpret_cast<const uint4v*>(src);
        }
        __syncthreads();
        short8 fAh[4], fAl[4], fBh[3], fBl[3];
        #pragma unroll
        for (int i = 0; i < 4; ++i) {
            int ra = wr*64 + i*16 + l15;
            fAh[i] = *reinterpret_cast<const short8*>(smem +     0 + ra*80 + l4*16);
            fAl[i] = *reinterpret_cast<const short8*>(smem + 10240 + ra*80 + l4*16);
        }
        #pragma unroll
        for (int i = 0; i < 3; ++i) {
            int rb = wc*48 + i*16 + l15;
            fBh[i] = *reinterpret_cast<const short8*>(smem + 20480 + rb*80 + l4*16);
            fBl[i] = *reinterpret_cast<const short8*>(smem + 28160 + rb*80 + l4*16);
        }
        #pragma unroll
        for (int io = 0; io < 4; ++io)
            #pragma unroll
            for (int jc = 0; jc < 3; ++jc) {
                acc[io][jc] = MFMA16(fAl[io], fBh[jc], acc[io][jc]);
                acc[io][jc] = MFMA16(fAh[io], fBl[jc], acc[io][jc]);
                acc[io][jc] = MFMA16(fAh[io], fBh[jc], acc[io][jc]);
            }
    }

    __syncthreads();
    float* sd = (float*)smem;
    #pragma unroll
    for (int io = 0; io < 4; ++io)
        #pragma unroll
        for (int jc = 0; jc < 3; ++jc) {
            int jj = wc*48 + jc*16 + l15;
            int orow = wr*64 + io*16 + l4*4;
            *reinterpret_cast<f32x4*>(sd + jj*132 + orow) = acc[io][jc];
        }
    __syncthreads();

    #pragma unroll
    for (int rep = 0; rep < 2; ++rep) {
        int task = tid + 256*rep;
        int oc = task & 15, nl = (task >> 4) & 31;
        float d[3][8], x[3][8];
        #pragma unroll
        for (int v = 0; v < 3; ++v) {
            const float* dp = sd + (v*32 + nl)*132 + oc*8;
            #pragma unroll
            for (int e = 0; e < 8; ++e) d[v][e] = dp[e];
        }
        if (VIRT && ob != 0) {
            #pragma unroll
            for (int e = 0; e < 8; ++e) {
                int c = oc*8 + e;
                #pragma unroll
                for (int v = 0; v < 3; ++v)
                    x[v][e] = Pm[(size_t)(b*128 + c)*3 + v];
            }
        } else {
            #pragma unroll
            for (int v = 0; v < 3; ++v) {
                size_t m = (size_t)(b*6144 + v*2048 + n0 + nl);
                uint4v hx = *reinterpret_cast<const uint4v*>(X1h + m*sx + ob + oc*8);
                uint4v lx = *reinterpret_cast<const uint4v*>(X1l + m*sx + ob + oc*8);
                #pragma unroll
                for (int w = 0; w < 4; ++w) {
                    x[v][2*w]   = bh2f(hx[w] & 0xffffu) + bh2f(lx[w] & 0xffffu);
                    x[v][2*w+1] = bh2f(hx[w] >> 16)     + bh2f(lx[w] >> 16);
                }
            }
        }
        #pragma unroll
        for (int e = 0; e < 8; ++e) {
            float d0 = d[0][e], d1 = d[1][e], d2 = d[2][e];
            float dot = x[0][e]*d0 + x[1][e]*d1 + x[2][e]*d2;
            float dsq = d0*d0 + d1*d1 + d2*d2;
            float t = dot / (dsq + EPSV);
            if (dot < 0.f) { x[0][e] -= t*d0; x[1][e] -= t*d1; x[2][e] -= t*d2; }
        }
        #pragma unroll
        for (int v = 0; v < 3; ++v) {
            u32 hw[4], lw[4];
            #pragma unroll
            for (int e2 = 0; e2 < 4; ++e2) {
                float y0 = x[v][2*e2], y1 = x[v][2*e2+1];
                u16 h0 = f2bh(y0), h1 = f2bh(y1);
                u16 q0 = f2bh(y0 - bh2f(h0)), q1 = f2bh(y1 - bh2f(h1));
                hw[e2] = (u32)h0 | ((u32)h1 << 16);
                lw[e2] = (u32)q0 | ((u32)q1 << 16);
            }
            size_t ooff = (size_t)(b*6144 + v*2048 + n0 + nl)*so + ob + oc*8;
            *reinterpret_cast<uint4v*>(Oh + ooff) = (uint4v){hw[0],hw[1],hw[2],hw[3]};
            *reinterpret_cast<uint4v*>(Ol + ooff) = (uint4v){lw[0],lw[1],lw[2],lw[3]};
        }
    }
}

// -------------------------------------------------- pooled mean finalization
__global__ __launch_bounds__(256)
void pfin_kernel(const float* __restrict__ Pacc, float* __restrict__ Pm) {
    int t = blockIdx.x*256 + threadIdx.x;
    if (t < BB*128*3) Pm[t] = Pacc[t] * (1.f / (float)NPT);
}

// --------- bias for virtualized concat: biasD = Wd0[:,128:]*P, biasS likewise
__global__ __launch_bounds__(96)
void bias_kernel(const float* __restrict__ wd0n, const float* __restrict__ wscn,
                 const float* __restrict__ Pm,
                 float* __restrict__ biasD, float* __restrict__ biasS) {
    int b = blockIdx.x;
    int slot = blockIdx.y*32 + threadIdx.x/3;
    int v = threadIdx.x % 3;
    const float* pmb = Pm + b*384;
    if (slot < 256) {
        const float* wrow = wd0n + (size_t)slot*256 + 128;
        float s = 0.f;
        for (int c = 0; c < 128; ++c) s += wrow[c]*pmb[c*3 + v];
        biasD[(size_t)(b*256 + slot)*3 + v] = s;
    } else {
        int o = slot - 256;
        const float* wrow = wscn + (size_t)o*256 + 128;
        float s = 0.f;
        for (int c = 0; c < 128; ++c) s += wrow[c]*pmb[c*3 + v];
        biasS[(size_t)(b*128 + o)*3 + v] = s;
    }
}

// ------------------------------------------------- weight split-bf16 convert
#define WO_FCPOS 0
#define WO_DIR0  32768
#define WO_FC0   360448
#define WO_DIR1  524288
#define WO_FC1   606208
#define WO_SC    688128
#define WTOT     851968
__global__ __launch_bounds__(256)
void convert_w_kernel(const float* __restrict__ s0, const float* __restrict__ s1,
                      const float* __restrict__ s2, const float* __restrict__ s3,
                      const float* __restrict__ s4, const float* __restrict__ s5,
                      u16* __restrict__ Wh, u16* __restrict__ Wl) {
    int t = blockIdx.x*256 + threadIdx.x;
    if (t >= WTOT) return;
    const float* src; int base;
    if      (t < WO_DIR0) { src = s0; base = WO_FCPOS; }
    else if (t < WO_FC0)  { src = s1; base = WO_DIR0; }
    else if (t < WO_DIR1) { src = s2; base = WO_FC0; }
    else if (t < WO_FC1)  { src = s3; base = WO_DIR1; }
    else if (t < WO_SC)   { src = s4; base = WO_FC1; }
    else                  { src = s5; base = WO_SC; }
    float v = src[t - base];
    u16 h = f2bh(v);
    Wh[t] = h;
    Wl[t] = f2bh(v - bh2f(h));
}

// ----------------------------------------------------- head: leaky(0.2)+fc_c
__global__ __launch_bounds__(128)
void final_head_kernel(const float* __restrict__ q, const float* __restrict__ Wdir,
                       const float* __restrict__ Wfc, float* __restrict__ out) {
    int b = blockIdx.x; int o = threadIdx.x;
    __shared__ float qs[128][3];
    __shared__ float zs[128][3];
    qs[o][0] = q[((size_t)b*128 + o)*3 + 0];
    qs[o][1] = q[((size_t)b*128 + o)*3 + 1];
    qs[o][2] = q[((size_t)b*128 + o)*3 + 2];
    __syncthreads();
    float d0 = 0.f, d1 = 0.f, d2 = 0.f;
    for (int c = 0; c < 128; ++c) {
        float w = Wdir[o*128 + c];
        d0 += w*qs[c][0]; d1 += w*qs[c][1]; d2 += w*qs[c][2];
    }
    float x0 = qs[o][0], x1 = qs[o][1], x2 = qs[o][2];
    float dot = d0*x0 + d1*x1 + d2*x2;
    float dsq = d0*d0 + d1*d1 + d2*d2;
    float t = dot / (dsq + EPSV);
    bool pos = dot >= 0.f;
    float g0 = pos ? x0 : (x0 - t*d0);
    float g1 = pos ? x1 : (x1 - t*d1);
    float g2 = pos ? x2 : (x2 - t*d2);
    zs[o][0] = 0.2f*x0 + 0.8f*g0;
    zs[o][1] = 0.2f*x1 + 0.8f*g1;
    zs[o][2] = 0.2f*x2 + 0.8f*g2;
    __syncthreads();
    float c0 = 0.f, c1 = 0.f, c2 = 0.f;
    for (int c = 0; c < 128; ++c) {
        float w = Wfc[o*128 + c];
        c0 += w*zs[c][0]; c1 += w*zs[c][1]; c2 += w*zs[c][2];
    }
    out[((size_t)b*128 + o)*3 + 0] = c0;
    out[((size_t)b*128 + o)*3 + 1] = c1;
    out[((size_t)b*128 + o)*3 + 2] = c2;
}

extern "C" void kernel_launch(void* const* d_in, const int* in_sizes, int n_in,
                              void* d_out, int out_size, void* d_ws, size_t ws_size,
                              hipStream_t stream) {
    const float* p           = (const float*)d_in[0];
    const float* w_conv_feat = (const float*)d_in[1];
    const float* w_conv_dir  = (const float*)d_in[2];
    const float* w_fc_pos    = (const float*)d_in[3];
    const float* blk_dir0    = (const float*)d_in[4];
    const float* blk_fc0     = (const float*)d_in[5];
    const float* blk_dir1    = (const float*)d_in[6];
    const float* blk_fc1     = (const float*)d_in[7];
    const float* blk_sc      = (const float*)d_in[8];
    const float* w_actc_dir  = (const float*)d_in[9];
    const float* w_fc_c      = (const float*)d_in[10];
    float* out = (float*)d_out;

    char* wsb = (char*)d_ws;
    size_t cur = 0;
    auto carve = [&](size_t nbytes) -> char* {
        char* r = wsb + cur;
        cur += (nbytes + 255) & ~(size_t)255;
        return r;
    };
    const size_t MTOT = (size_t)BB*3*NPT;      // 24576 columns
    int*   idx   = (int*)  carve((size_t)BB*NPT*KNN*4);
    float* Pacc  = (float*)carve(1536*4);
    float* Pm    = (float*)carve(1536*4);
    float* biasD = (float*)carve((size_t)BB*256*3*4);
    float* biasS = (float*)carve((size_t)BB*128*3*4);
    u16* Wh    = (u16*)carve((size_t)WTOT*2);
    u16* Wl    = (u16*)carve((size_t)WTOT*2);
    u16* net1h = (u16*)carve(MTOT*128*2);      // also T
    u16* net1l = (u16*)carve(MTOT*128*2);
    u16* X0h   = (u16*)carve(MTOT*256*2);      // also Y-alt (front half)
    u16* X0l   = (u16*)carve(MTOT*256*2);
    u16* Abh   = (u16*)carve(MTOT*256*2);      // A; also U (front half)
    u16* Abl   = (u16*)carve(MTOT*256*2);
    u16* Ybh   = (u16*)carve(MTOT*128*2);
    u16* Ybl   = (u16*)carve(MTOT*128*2);

    convert_w_kernel<<<(WTOT+255)/256, 256, 0, stream>>>(
        w_fc_pos, blk_dir0, blk_fc0, blk_dir1, blk_fc1, blk_sc, Wh, Wl);
    knn_kernel<<<BB*NPT, 256, 0, stream>>>(p, idx);
    edgeconv_kernel<<<BB*NPT, 128, 0, stream>>>(p, idx, w_conv_feat, w_conv_dir, net1h, net1l);

    // fc_pos: [256 x 128] x net1 -> X0
    gemm_plain<256,128,0,false,false><<<dim3(192,2), 256, 0, stream>>>(
        Wh+WO_FCPOS, Wl+WO_FCPOS, 128, net1h, net1l, 128,
        nullptr, nullptr, 0, nullptr, nullptr, 0,
        nullptr, X0h, X0l, 256, nullptr);

    const u16 *Yph = nullptr, *Ypl = nullptr;
    for (int i = 0; i < 5; ++i) {
        hipMemsetAsync(Pacc, 0, 1536*4, stream);
        size_t od0 = WO_DIR0 + (size_t)i*65536;
        size_t of0 = WO_FC0  + (size_t)i*32768;
        size_t od1 = WO_DIR1 + (size_t)i*16384;
        size_t of1 = WO_FC1  + (size_t)i*16384;
        size_t osc = WO_SC   + (size_t)i*32768;

        if (i == 0) {
            gemm_dir<256,256,false><<<dim3(BB*64,2), 256, 0, stream>>>(
                Wh+od0, Wl+od0, 256, X0h, X0l, 256, nullptr, nullptr, Abh, Abl, 256);
        } else {
            gemm_dir<256,128,true><<<dim3(BB*64,2), 256, 0, stream>>>(
                Wh+od0, Wl+od0, 256, Yph, Ypl, 128, biasD, Pm, Abh, Abl, 256);
        }
        gemm_plain<128,256,0,false,false><<<dim3(192,1), 256, 0, stream>>>(
            Wh+of0, Wl+of0, 256, Abh, Abl, 256,
            nullptr, nullptr, 0, nullptr, nullptr, 0,
            nullptr, net1h, net1l, 128, nullptr);
        gemm_dir<128,128,false><<<dim3(BB*64,1), 256, 0, stream>>>(
            Wh+od1, Wl+od1, 128, net1h, net1l, 128, nullptr, nullptr, Abh, Abl, 128);

        u16* outh = (i % 2 == 0) ? Ybh : X0h;
        u16* outl = (i % 2 == 0) ? Ybl : X0l;
        if (i == 0) {
            gemm_plain<128,128,256,true,false><<<dim3(192,1), 256, 0, stream>>>(
                Wh+of1, Wl+of1, 128, Abh, Abl, 128,
                Wh+osc, Wl+osc, 256, X0h, X0l, 256,
                nullptr, outh, outl, 128, Pacc);
        } else {
            gemm_plain<128,128,128,true,true><<<dim3(192,1), 256, 0, stream>>>(
                Wh+of1, Wl+of1, 128, Abh, Abl, 128,
                Wh+osc, Wl+osc, 256, Yph, Ypl, 128,
                biasS, outh, outl, 128, Pacc);
        }
        pfin_kernel<<<6, 256, 0, stream>>>(Pacc, Pm);
        if (i < 4) {
            bias_kernel<<<dim3(BB,12), 96, 0, stream>>>(
                blk_dir0 + (size_t)(i+1)*65536, blk_sc + (size_t)(i+1)*32768,
                Pm, biasD, biasS);
        }
        Yph = outh; Ypl = outl;
    }

    final_head_kernel<<<BB, 128, 0, stream>>>(Pm, w_actc_dir, w_fc_c, out);
}

// Round 3
// 552.374 us; speedup vs baseline: 1.9201x; 1.0415x over previous
//
#include <hip/hip_runtime.h>
#include <math.h>

#define NPT 2048
#define BB 4
#define KNN 20
#define EPSV 1e-6f

typedef unsigned short u16;
typedef unsigned int u32;
typedef __attribute__((ext_vector_type(8))) short short8;
typedef __attribute__((ext_vector_type(4))) float f32x4;
typedef __attribute__((ext_vector_type(4))) u32 uint4v;

#define MFMA16(a,b,c) __builtin_amdgcn_mfma_f32_16x16x32_bf16((a),(b),(c),0,0,0)

__device__ __forceinline__ u16 f2bh(float f) {
    u32 u = __builtin_bit_cast(u32, f);
    return (u16)((u + 0x7FFFu + ((u >> 16) & 1u)) >> 16);
}
__device__ __forceinline__ float bh2f(u32 hbits) {
    return __builtin_bit_cast(float, hbits << 16);
}

// ------------------------------------------------ kNN top-20 via radix-select
__global__ __launch_bounds__(256)
void knn_kernel(const float* __restrict__ p, int* __restrict__ idx) {
    int bn = blockIdx.x;
    int b = bn >> 11, n = bn & (NPT - 1);
    const float* pb = p + (size_t)b * NPT * 3;
    float qx = pb[n*3+0], qy = pb[n*3+1], qz = pb[n*3+2];
    float qq = qx*qx + qy*qy + qz*qz;
    __shared__ u32 keys[NPT];
    __shared__ int hist[256];
    __shared__ int wtot[4];
    __shared__ int sh_byte, sh_ngt, sure_cnt, tie_cnt;
    __shared__ int tie_m[64];
    int tid = threadIdx.x;
    int lane = tid & 63, wv = tid >> 6;
    for (int m = tid; m < NPT; m += 256) {
        float px = pb[m*3+0], py = pb[m*3+1], pz = pb[m*3+2];
        float sc = 2.f*(qx*px + qy*py + qz*pz) - qq - (px*px + py*py + pz*pz);
        u32 u = __builtin_bit_cast(u32, sc);
        keys[m] = u ^ (u32)(((int)u >> 31) | (int)0x80000000);
    }
    if (tid == 0) { sure_cnt = 0; tie_cnt = 0; }
    __syncthreads();
    u32 prefix = 0; int need = KNN;
    for (int pass = 3; pass >= 0; --pass) {
        int shift = pass * 8;
        u32 maskhi = (pass == 3) ? 0u : (0xFFFFFFFFu << (shift + 8));
        hist[tid] = 0;
        __syncthreads();
        #pragma unroll
        for (int j = 0; j < 8; ++j) {
            u32 key = keys[tid + 256*j];
            if ((key & maskhi) == (prefix & maskhi))
                atomicAdd(&hist[(key >> shift) & 255], 1);
        }
        __syncthreads();
        int own = hist[tid];
        int sum = own;
        #pragma unroll
        for (int off = 1; off < 64; off <<= 1) {
            int v = __shfl_down(sum, off, 64);
            if (lane + off < 64) sum += v;
        }
        if (lane == 0) wtot[wv] = sum;
        __syncthreads();
        int addhi = 0;
        #pragma unroll
        for (int w2 = 0; w2 < 4; ++w2) if (w2 > wv) addhi += wtot[w2];
        int cnt_ge = sum + addhi;
        int cnt_gt = cnt_ge - own;
        if (cnt_ge >= need && cnt_gt < need) { sh_byte = tid; sh_ngt = cnt_gt; }
        __syncthreads();
        prefix |= ((u32)sh_byte) << shift;
        need -= sh_ngt;
        __syncthreads();
    }
    u32 T = prefix;
    #pragma unroll
    for (int j = 0; j < 8; ++j) {
        int m = tid + 256*j;
        u32 key = keys[m];
        if (key > T) {
            int slot = atomicAdd(&sure_cnt, 1);
            idx[(size_t)bn*KNN + slot] = m;
        } else if (key == T) {
            int t = atomicAdd(&tie_cnt, 1);
            if (t < 64) tie_m[t] = m;
        }
    }
    __syncthreads();
    if (tid == 0) {
        int base = sure_cnt;         // == KNN - need
        int r = KNN - base;
        int tc = tie_cnt;
        if (tc == r) {
            for (int t2 = 0; t2 < r; ++t2) idx[(size_t)bn*KNN + base + t2] = tie_m[t2];
        } else if (tc <= 64) {
            for (int t2 = 0; t2 < r; ++t2) {
                int best = 1 << 30, bj = 0;
                for (int t3 = 0; t3 < tc; ++t3)
                    if (tie_m[t3] < best) { best = tie_m[t3]; bj = t3; }
                tie_m[bj] = 1 << 30;
                idx[(size_t)bn*KNN + base + t2] = best;
            }
        } else {
            int got = 0;
            for (int m = 0; m < NPT && got < r; ++m)
                if (keys[m] == T) { idx[(size_t)bn*KNN + base + got] = m; ++got; }
        }
    }
}

// ---------------------- edge conv + leaky(0.2) + mean_k -> split-bf16 K-major
__global__ __launch_bounds__(128)
void edgeconv_kernel(const float* __restrict__ p, const int* __restrict__ idx,
                     const float* __restrict__ wf, const float* __restrict__ wd,
                     u16* __restrict__ net1h, u16* __restrict__ net1l) {
    int bn = blockIdx.x;
    int b = bn >> 11, n = bn & (NPT - 1);
    __shared__ float nb[KNN][3];
    __shared__ float ctr[3];
    int tid = threadIdx.x;
    if (tid < KNN) {
        int j = idx[(size_t)bn*KNN + tid];
        const float* pj = p + ((size_t)b*NPT + j)*3;
        nb[tid][0] = pj[0]; nb[tid][1] = pj[1]; nb[tid][2] = pj[2];
    }
    if (tid >= 64 && tid < 67) ctr[tid-64] = p[((size_t)b*NPT + n)*3 + (tid-64)];
    __syncthreads();
    int o = tid;
    float wfa = wf[o*3+0], wfb = wf[o*3+1], wfc = wf[o*3+2];
    float wda = wd[o*3+0], wdb = wd[o*3+1], wdc = wd[o*3+2];
    float cx = ctr[0], cy = ctr[1], cz = ctr[2];
    float a0 = 0.f, a1 = 0.f, a2 = 0.f;
    #pragma unroll 4
    for (int k = 0; k < KNN; ++k) {
        float nx = nb[k][0], ny = nb[k][1], nz = nb[k][2];
        float rx = nx-cx, ry = ny-cy, rz = nz-cz;
        float sx = ny*cz - nz*cy;
        float sy = nz*cx - nx*cz;
        float sz = nx*cy - ny*cx;
        float fx = wfa*rx + wfb*cx + wfc*sx;
        float fy = wfa*ry + wfb*cy + wfc*sy;
        float fz = wfa*rz + wfb*cz + wfc*sz;
        float dx0 = wda*rx + wdb*cx + wdc*sx;
        float dy0 = wda*ry + wdb*cy + wdc*sy;
        float dz0 = wda*rz + wdb*cz + wdc*sz;
        float dot = fx*dx0 + fy*dy0 + fz*dz0;
        float dsq = dx0*dx0 + dy0*dy0 + dz0*dz0;
        float t = dot / (dsq + EPSV);
        bool pos = dot >= 0.f;
        float gx = pos ? fx : (fx - t*dx0);
        float gy = pos ? fy : (fy - t*dy0);
        float gz = pos ? fz : (fz - t*dz0);
        a0 += 0.2f*fx + 0.8f*gx;
        a1 += 0.2f*fy + 0.8f*gy;
        a2 += 0.2f*fz + 0.8f*gz;
    }
    const float s = 1.f / (float)KNN;
    float av[3] = {a0*s, a1*s, a2*s};
    #pragma unroll
    for (int v = 0; v < 3; ++v) {
        u16 h = f2bh(av[v]);
        u16 l = f2bh(av[v] - bh2f(h));
        size_t off = (size_t)(b*6144 + v*2048 + n)*128 + o;
        net1h[off] = h; net1l[off] = l;
    }
}

// ------------------------------------------------------ MFMA split-bf16 GEMM
// Y[o, m] = W1*X1 (+ W2*X2) (+ bias from fp32 Wsc[:,128:]*Pm); optional pool.
// Activations K-major: X[m][c], m = b*6144 + vec*2048 + n. Block: 128o x 128m.
template<int O, int C1, int C2, bool POOL, bool BIASED>
__global__ __launch_bounds__(256) void gemm_plain(
    const u16* __restrict__ W1h, const u16* __restrict__ W1l, int ldw1,
    const u16* __restrict__ X1h, const u16* __restrict__ X1l, int sx1,
    const u16* __restrict__ W2h, const u16* __restrict__ W2l, int ldw2,
    const u16* __restrict__ X2h, const u16* __restrict__ X2l, int sx2,
    const float* __restrict__ WscF, const float* __restrict__ PmPrev,
    u16* __restrict__ Yh, u16* __restrict__ Yl, int sy,
    float* __restrict__ PmOut)
{
    __shared__ __align__(16) char smem[128*132*4];
    __shared__ float pms[128];
    __shared__ float biasS_s[128];
    const int m0 = blockIdx.x * 128;
    const int ob = blockIdx.y * 128;
    const int b   = m0 / 6144;
    const int vec = (m0 % 6144) / 2048;
    const int tid = threadIdx.x;
    const int lane = tid & 63;
    const int wid = __builtin_amdgcn_readfirstlane(tid >> 6);
    const int wr = wid & 1, wc = wid >> 1;
    const int l15 = lane & 15, l4 = lane >> 4;

    if (BIASED) {
        if (tid < 128) pms[tid] = PmPrev[(size_t)(b*128 + tid)*3 + vec];
        __syncthreads();
        if (tid < 128) {
            const float* wrow = WscF + (size_t)tid*256 + 128;
            float s = 0.f;
            #pragma unroll 4
            for (int c = 0; c < 128; ++c) s += wrow[c]*pms[c];
            biasS_s[tid] = s;
        }
        __syncthreads();
    }

    f32x4 acc[4][4];
    #pragma unroll
    for (int io = 0; io < 4; ++io) {
        float bv[4];
        #pragma unroll
        for (int r = 0; r < 4; ++r)
            bv[r] = BIASED ? biasS_s[wr*64 + io*16 + l4*4 + r] : 0.f;
        #pragma unroll
        for (int jc = 0; jc < 4; ++jc)
            #pragma unroll
            for (int r = 0; r < 4; ++r) acc[io][jc][r] = bv[r];
    }

    constexpr int NS = C1/32 + C2/32;
    auto ldaddr = [&](int st, int u) -> const u16* {
        const bool ph2 = (st >= C1/32);
        const u16* wh = ph2 ? W2h : W1h; const u16* wl = ph2 ? W2l : W1l;
        const u16* xh = ph2 ? X2h : X1h; const u16* xl = ph2 ? X2l : X1l;
        int ldw = ph2 ? ldw2 : ldw1; int sx = ph2 ? sx2 : sx1;
        int cc = (ph2 ? (st - C1/32) : st) * 32;
        int pl = u >> 9, id = u & 511, row = id >> 2, q = id & 3;
        if (pl == 0) return wh + (size_t)(ob + row)*ldw + cc + q*8;
        if (pl == 1) return wl + (size_t)(ob + row)*ldw + cc + q*8;
        if (pl == 2) return xh + (size_t)(m0 + row)*sx + cc + q*8;
        return xl + (size_t)(m0 + row)*sx + cc + q*8;
    };
    auto lds_dst = [&](int u) -> char* {
        int pl = u >> 9, id = u & 511, row = id >> 2, q = id & 3;
        return smem + pl*10240 + row*80 + q*16;
    };

    uint4v pf[8];
    #pragma unroll
    for (int j = 0; j < 8; ++j) pf[j] = *reinterpret_cast<const uint4v*>(ldaddr(0, tid + 256*j));
    #pragma unroll
    for (int j = 0; j < 8; ++j) *reinterpret_cast<uint4v*>(lds_dst(tid + 256*j)) = pf[j];

    for (int st = 0; st < NS; ++st) {
        __syncthreads();
        if (st + 1 < NS) {
            #pragma unroll
            for (int j = 0; j < 8; ++j)
                pf[j] = *reinterpret_cast<const uint4v*>(ldaddr(st+1, tid + 256*j));
        }
        short8 fAh[4], fAl[4], fBh[4], fBl[4];
        #pragma unroll
        for (int i = 0; i < 4; ++i) {
            int ra = wr*64 + i*16 + l15;
            fAh[i] = *reinterpret_cast<const short8*>(smem +     0 + ra*80 + l4*16);
            fAl[i] = *reinterpret_cast<const short8*>(smem + 10240 + ra*80 + l4*16);
            int rb = wc*64 + i*16 + l15;
            fBh[i] = *reinterpret_cast<const short8*>(smem + 20480 + rb*80 + l4*16);
            fBl[i] = *reinterpret_cast<const short8*>(smem + 30720 + rb*80 + l4*16);
        }
        #pragma unroll
        for (int io = 0; io < 4; ++io)
            #pragma unroll
            for (int jc = 0; jc < 4; ++jc) {
                acc[io][jc] = MFMA16(fAl[io], fBh[jc], acc[io][jc]);
                acc[io][jc] = MFMA16(fAh[io], fBl[jc], acc[io][jc]);
                acc[io][jc] = MFMA16(fAh[io], fBh[jc], acc[io][jc]);
            }
        __syncthreads();
        if (st + 1 < NS) {
            #pragma unroll
            for (int j = 0; j < 8; ++j)
                *reinterpret_cast<uint4v*>(lds_dst(tid + 256*j)) = pf[j];
        }
    }

    float* sd = (float*)smem;
    #pragma unroll
    for (int io = 0; io < 4; ++io)
        #pragma unroll
        for (int jc = 0; jc < 4; ++jc) {
            int jj = wc*64 + jc*16 + l15;
            int orow = wr*64 + io*16 + l4*4;
            *reinterpret_cast<f32x4*>(sd + jj*132 + orow) = acc[io][jc];
        }
    __syncthreads();

    #pragma unroll
    for (int rep = 0; rep < 8; ++rep) {
        int task = tid + 256*rep;
        int oc = task & 15, ml = task >> 4;
        const float* dp = sd + ml*132 + oc*8;
        u32 hw[4], lw[4];
        #pragma unroll
        for (int e2 = 0; e2 < 4; ++e2) {
            float y0 = dp[2*e2], y1 = dp[2*e2+1];
            u16 h0 = f2bh(y0), h1 = f2bh(y1);
            u16 q0 = f2bh(y0 - bh2f(h0)), q1 = f2bh(y1 - bh2f(h1));
            hw[e2] = (u32)h0 | ((u32)h1 << 16);
            lw[e2] = (u32)q0 | ((u32)q1 << 16);
        }
        size_t ooff = (size_t)(m0 + ml)*sy + ob + oc*8;
        *reinterpret_cast<uint4v*>(Yh + ooff) = (uint4v){hw[0],hw[1],hw[2],hw[3]};
        *reinterpret_cast<uint4v*>(Yl + ooff) = (uint4v){lw[0],lw[1],lw[2],lw[3]};
    }

    if (POOL) {
        int o_l = tid & 127, half = tid >> 7;
        float sum = 0.f;
        #pragma unroll 8
        for (int c = 0; c < 64; ++c) sum += sd[(half*64 + c)*132 + o_l];
        atomicAdd(&PmOut[(size_t)(b*128 + o_l)*3 + vec], sum * (1.f/(float)NPT));
    }
}

// ------------------- MFMA split-bf16 dir GEMM + fused VN-leaky(0) epilogue
// Block: 128o x 96cols (3 vec strips x 32 n). VIRT: concat-half via fp32 bias.
template<int O, int CIN, bool VIRT>
__global__ __launch_bounds__(256) void gemm_dir(
    const u16* __restrict__ Wh_, const u16* __restrict__ Wl_, int ldw,
    const u16* __restrict__ X1h, const u16* __restrict__ X1l, int sx,
    const float* __restrict__ WdF, const float* __restrict__ Pm,
    u16* __restrict__ Oh, u16* __restrict__ Ol, int so)
{
    __shared__ __align__(16) char smem[96*132*4];
    __shared__ float pmd[384];
    __shared__ float biasD_s[384];
    const int gx = blockIdx.x;
    const int b  = gx >> 6;
    const int n0 = (gx & 63) * 32;
    const int ob = blockIdx.y * 128;
    const int tid = threadIdx.x;
    const int lane = tid & 63;
    const int wid = __builtin_amdgcn_readfirstlane(tid >> 6);
    const int wr = wid & 1, wc = wid >> 1;
    const int l15 = lane & 15, l4 = lane >> 4;

    if (VIRT) {
        for (int t = tid; t < 384; t += 256) pmd[t] = Pm[(size_t)b*384 + t];
        __syncthreads();
        for (int t = tid; t < 384; t += 256) {
            int o_l = t / 3, v = t - o_l*3;
            const float* wrow = WdF + (size_t)(ob + o_l)*256 + 128;
            float s = 0.f;
            #pragma unroll 4
            for (int c = 0; c < 128; ++c) s += wrow[c]*pmd[c*3 + v];
            biasD_s[t] = s;
        }
        __syncthreads();
    }

    f32x4 acc[4][3];
    #pragma unroll
    for (int io = 0; io < 4; ++io)
        #pragma unroll
        for (int jc = 0; jc < 3; ++jc) {
            int v = (wc*48 + jc*16) >> 5;
            #pragma unroll
            for (int r = 0; r < 4; ++r) {
                int o_l = wr*64 + io*16 + l4*4 + r;
                acc[io][jc][r] = VIRT ? biasD_s[o_l*3 + v] : 0.f;
            }
        }

    auto ldaddr = [&](int st, int u) -> const u16* {
        int cc = st*32;
        if (u < 1024) {
            int pl = u >> 9, id = u & 511, row = id >> 2, q = id & 3;
            return (pl ? Wl_ : Wh_) + (size_t)(ob + row)*ldw + cc + q*8;
        }
        int uu = u - 1024;
        int pl = (uu >= 384) ? 1 : 0;
        int id = pl ? uu - 384 : uu;
        int row = id >> 2, q = id & 3;
        int m = b*6144 + (row >> 5)*2048 + n0 + (row & 31);
        return (pl ? X1l : X1h) + (size_t)m*sx + cc + q*8;
    };
    auto lds_dst = [&](int u) -> char* {
        if (u < 1024) {
            int pl = u >> 9, id = u & 511, row = id >> 2, q = id & 3;
            return smem + pl*10240 + row*80 + q*16;
        }
        int uu = u - 1024;
        int pl = (uu >= 384) ? 1 : 0;
        int id = pl ? uu - 384 : uu;
        int row = id >> 2, q = id & 3;
        return smem + 20480 + pl*7680 + row*80 + q*16;
    };

    constexpr int NS = CIN/32;
    uint4v pf[7];
    #pragma unroll
    for (int j = 0; j < 7; ++j) pf[j] = *reinterpret_cast<const uint4v*>(ldaddr(0, tid + 256*j));
    #pragma unroll
    for (int j = 0; j < 7; ++j) *reinterpret_cast<uint4v*>(lds_dst(tid + 256*j)) = pf[j];

    for (int st = 0; st < NS; ++st) {
        __syncthreads();
        if (st + 1 < NS) {
            #pragma unroll
            for (int j = 0; j < 7; ++j)
                pf[j] = *reinterpret_cast<const uint4v*>(ldaddr(st+1, tid + 256*j));
        }
        short8 fAh[4], fAl[4], fBh[3], fBl[3];
        #pragma unroll
        for (int i = 0; i < 4; ++i) {
            int ra = wr*64 + i*16 + l15;
            fAh[i] = *reinterpret_cast<const short8*>(smem +     0 + ra*80 + l4*16);
            fAl[i] = *reinterpret_cast<const short8*>(smem + 10240 + ra*80 + l4*16);
        }
        #pragma unroll
        for (int i = 0; i < 3; ++i) {
            int rb = wc*48 + i*16 + l15;
            fBh[i] = *reinterpret_cast<const short8*>(smem + 20480 + rb*80 + l4*16);
            fBl[i] = *reinterpret_cast<const short8*>(smem + 28160 + rb*80 + l4*16);
        }
        #pragma unroll
        for (int io = 0; io < 4; ++io)
            #pragma unroll
            for (int jc = 0; jc < 3; ++jc) {
                acc[io][jc] = MFMA16(fAl[io], fBh[jc], acc[io][jc]);
                acc[io][jc] = MFMA16(fAh[io], fBl[jc], acc[io][jc]);
                acc[io][jc] = MFMA16(fAh[io], fBh[jc], acc[io][jc]);
            }
        __syncthreads();
        if (st + 1 < NS) {
            #pragma unroll
            for (int j = 0; j < 7; ++j)
                *reinterpret_cast<uint4v*>(lds_dst(tid + 256*j)) = pf[j];
        }
    }

    float* sd = (float*)smem;
    #pragma unroll
    for (int io = 0; io < 4; ++io)
        #pragma unroll
        for (int jc = 0; jc < 3; ++jc) {
            int jj = wc*48 + jc*16 + l15;
            int orow = wr*64 + io*16 + l4*4;
            *reinterpret_cast<f32x4*>(sd + jj*132 + orow) = acc[io][jc];
        }
    __syncthreads();

    #pragma unroll
    for (int rep = 0; rep < 2; ++rep) {
        int task = tid + 256*rep;
        int oc = task & 15, nl = (task >> 4) & 31;
        float d[3][8], x[3][8];
        #pragma unroll
        for (int v = 0; v < 3; ++v) {
            const float* dp = sd + (v*32 + nl)*132 + oc*8;
            #pragma unroll
            for (int e = 0; e < 8; ++e) d[v][e] = dp[e];
        }
        if (VIRT && ob != 0) {
            #pragma unroll
            for (int e = 0; e < 8; ++e) {
                int c = oc*8 + e;
                #pragma unroll
                for (int v = 0; v < 3; ++v)
                    x[v][e] = Pm[(size_t)(b*128 + c)*3 + v];
            }
        } else {
            #pragma unroll
            for (int v = 0; v < 3; ++v) {
                size_t m = (size_t)(b*6144 + v*2048 + n0 + nl);
                uint4v hx = *reinterpret_cast<const uint4v*>(X1h + m*sx + ob + oc*8);
                uint4v lx = *reinterpret_cast<const uint4v*>(X1l + m*sx + ob + oc*8);
                #pragma unroll
                for (int w = 0; w < 4; ++w) {
                    x[v][2*w]   = bh2f(hx[w] & 0xffffu) + bh2f(lx[w] & 0xffffu);
                    x[v][2*w+1] = bh2f(hx[w] >> 16)     + bh2f(lx[w] >> 16);
                }
            }
        }
        #pragma unroll
        for (int e = 0; e < 8; ++e) {
            float d0 = d[0][e], d1 = d[1][e], d2 = d[2][e];
            float dot = x[0][e]*d0 + x[1][e]*d1 + x[2][e]*d2;
            float dsq = d0*d0 + d1*d1 + d2*d2;
            float t = dot / (dsq + EPSV);
            if (dot < 0.f) { x[0][e] -= t*d0; x[1][e] -= t*d1; x[2][e] -= t*d2; }
        }
        #pragma unroll
        for (int v = 0; v < 3; ++v) {
            u32 hw[4], lw[4];
            #pragma unroll
            for (int e2 = 0; e2 < 4; ++e2) {
                float y0 = x[v][2*e2], y1 = x[v][2*e2+1];
                u16 h0 = f2bh(y0), h1 = f2bh(y1);
                u16 q0 = f2bh(y0 - bh2f(h0)), q1 = f2bh(y1 - bh2f(h1));
                hw[e2] = (u32)h0 | ((u32)h1 << 16);
                lw[e2] = (u32)q0 | ((u32)q1 << 16);
            }
            size_t ooff = (size_t)(b*6144 + v*2048 + n0 + nl)*so + ob + oc*8;
            *reinterpret_cast<uint4v*>(Oh + ooff) = (uint4v){hw[0],hw[1],hw[2],hw[3]};
            *reinterpret_cast<uint4v*>(Ol + ooff) = (uint4v){lw[0],lw[1],lw[2],lw[3]};
        }
    }
}

// ------------------------------------------------- weight split-bf16 convert
#define WO_FCPOS 0
#define WO_DIR0  32768
#define WO_FC0   360448
#define WO_DIR1  524288
#define WO_FC1   606208
#define WO_SC    688128
#define WTOT     851968
__global__ __launch_bounds__(256)
void convert_w_kernel(const float* __restrict__ s0, const float* __restrict__ s1,
                      const float* __restrict__ s2, const float* __restrict__ s3,
                      const float* __restrict__ s4, const float* __restrict__ s5,
                      u16* __restrict__ Wh, u16* __restrict__ Wl) {
    int t = blockIdx.x*256 + threadIdx.x;
    if (t >= WTOT) return;
    const float* src; int base;
    if      (t < WO_DIR0) { src = s0; base = WO_FCPOS; }
    else if (t < WO_FC0)  { src = s1; base = WO_DIR0; }
    else if (t < WO_DIR1) { src = s2; base = WO_FC0; }
    else if (t < WO_FC1)  { src = s3; base = WO_DIR1; }
    else if (t < WO_SC)   { src = s4; base = WO_FC1; }
    else                  { src = s5; base = WO_SC; }
    float v = src[t - base];
    u16 h = f2bh(v);
    Wh[t] = h;
    Wl[t] = f2bh(v - bh2f(h));
}

// ----------------------------------------------------- head: leaky(0.2)+fc_c
__global__ __launch_bounds__(128)
void final_head_kernel(const float* __restrict__ q, const float* __restrict__ Wdir,
                       const float* __restrict__ Wfc, float* __restrict__ out) {
    int b = blockIdx.x; int o = threadIdx.x;
    __shared__ float qs[128][3];
    __shared__ float zs[128][3];
    qs[o][0] = q[((size_t)b*128 + o)*3 + 0];
    qs[o][1] = q[((size_t)b*128 + o)*3 + 1];
    qs[o][2] = q[((size_t)b*128 + o)*3 + 2];
    __syncthreads();
    float d0 = 0.f, d1 = 0.f, d2 = 0.f;
    for (int c = 0; c < 128; ++c) {
        float w = Wdir[o*128 + c];
        d0 += w*qs[c][0]; d1 += w*qs[c][1]; d2 += w*qs[c][2];
    }
    float x0 = qs[o][0], x1 = qs[o][1], x2 = qs[o][2];
    float dot = d0*x0 + d1*x1 + d2*x2;
    float dsq = d0*d0 + d1*d1 + d2*d2;
    float t = dot / (dsq + EPSV);
    bool pos = dot >= 0.f;
    float g0 = pos ? x0 : (x0 - t*d0);
    float g1 = pos ? x1 : (x1 - t*d1);
    float g2 = pos ? x2 : (x2 - t*d2);
    zs[o][0] = 0.2f*x0 + 0.8f*g0;
    zs[o][1] = 0.2f*x1 + 0.8f*g1;
    zs[o][2] = 0.2f*x2 + 0.8f*g2;
    __syncthreads();
    float c0 = 0.f, c1 = 0.f, c2 = 0.f;
    for (int c = 0; c < 128; ++c) {
        float w = Wfc[o*128 + c];
        c0 += w*zs[c][0]; c1 += w*zs[c][1]; c2 += w*zs[c][2];
    }
    out[((size_t)b*128 + o)*3 + 0] = c0;
    out[((size_t)b*128 + o)*3 + 1] = c1;
    out[((size_t)b*128 + o)*3 + 2] = c2;
}

extern "C" void kernel_launch(void* const* d_in, const int* in_sizes, int n_in,
                              void* d_out, int out_size, void* d_ws, size_t ws_size,
                              hipStream_t stream) {
    const float* p           = (const float*)d_in[0];
    const float* w_conv_feat = (const float*)d_in[1];
    const float* w_conv_dir  = (const float*)d_in[2];
    const float* w_fc_pos    = (const float*)d_in[3];
    const float* blk_dir0    = (const float*)d_in[4];
    const float* blk_fc0     = (const float*)d_in[5];
    const float* blk_dir1    = (const float*)d_in[6];
    const float* blk_fc1     = (const float*)d_in[7];
    const float* blk_sc      = (const float*)d_in[8];
    const float* w_actc_dir  = (const float*)d_in[9];
    const float* w_fc_c      = (const float*)d_in[10];
    float* out = (float*)d_out;

    char* wsb = (char*)d_ws;
    size_t cur = 0;
    auto carve = [&](size_t nbytes) -> char* {
        char* r = wsb + cur;
        cur += (nbytes + 255) & ~(size_t)255;
        return r;
    };
    const size_t MTOT = (size_t)BB*3*NPT;      // 24576 columns
    int*   idx   = (int*)  carve((size_t)BB*NPT*KNN*4);
    float* Pm0   = (float*)carve(1536*4);
    float* Pm1   = (float*)carve(1536*4);
    u16* Wh    = (u16*)carve((size_t)WTOT*2);
    u16* Wl    = (u16*)carve((size_t)WTOT*2);
    u16* net1h = (u16*)carve(MTOT*128*2);      // also T
    u16* net1l = (u16*)carve(MTOT*128*2);
    u16* X0h   = (u16*)carve(MTOT*256*2);      // also Y-alt (front half)
    u16* X0l   = (u16*)carve(MTOT*256*2);
    u16* Abh   = (u16*)carve(MTOT*256*2);      // A; also U (front half)
    u16* Abl   = (u16*)carve(MTOT*256*2);
    u16* Ybh   = (u16*)carve(MTOT*128*2);
    u16* Ybl   = (u16*)carve(MTOT*128*2);
    float* PmBuf[2] = { Pm0, Pm1 };

    convert_w_kernel<<<(WTOT+255)/256, 256, 0, stream>>>(
        w_fc_pos, blk_dir0, blk_fc0, blk_dir1, blk_fc1, blk_sc, Wh, Wl);
    knn_kernel<<<BB*NPT, 256, 0, stream>>>(p, idx);
    edgeconv_kernel<<<BB*NPT, 128, 0, stream>>>(p, idx, w_conv_feat, w_conv_dir, net1h, net1l);

    // fc_pos: [256 x 128] x net1 -> X0
    gemm_plain<256,128,0,false,false><<<dim3(192,2), 256, 0, stream>>>(
        Wh+WO_FCPOS, Wl+WO_FCPOS, 128, net1h, net1l, 128,
        nullptr, nullptr, 0, nullptr, nullptr, 0,
        nullptr, nullptr, X0h, X0l, 256, nullptr);

    const u16 *Yph = nullptr, *Ypl = nullptr;
    for (int i = 0; i < 5; ++i) {
        size_t od0 = WO_DIR0 + (size_t)i*65536;
        size_t of0 = WO_FC0  + (size_t)i*32768;
        size_t od1 = WO_DIR1 + (size_t)i*16384;
        size_t of1 = WO_FC1  + (size_t)i*16384;
        size_t osc = WO_SC   + (size_t)i*32768;
        float* PmPrev = PmBuf[(i+1) & 1];      // written by iteration i-1
        float* PmCur  = PmBuf[i & 1];

        if (i == 0) {
            gemm_dir<256,256,false><<<dim3(BB*64,2), 256, 0, stream>>>(
                Wh+od0, Wl+od0, 256, X0h, X0l, 256, nullptr, nullptr, Abh, Abl, 256);
        } else {
            gemm_dir<256,128,true><<<dim3(BB*64,2), 256, 0, stream>>>(
                Wh+od0, Wl+od0, 256, Yph, Ypl, 128,
                blk_dir0 + (size_t)i*65536, PmPrev, Abh, Abl, 256);
        }
        gemm_plain<128,256,0,false,false><<<dim3(192,1), 256, 0, stream>>>(
            Wh+of0, Wl+of0, 256, Abh, Abl, 256,
            nullptr, nullptr, 0, nullptr, nullptr, 0,
            nullptr, nullptr, net1h, net1l, 128, nullptr);
        gemm_dir<128,128,false><<<dim3(BB*64,1), 256, 0, stream>>>(
            Wh+od1, Wl+od1, 128, net1h, net1l, 128, nullptr, nullptr, Abh, Abl, 128);

        hipMemsetAsync(PmCur, 0, 1536*4, stream);
        u16* outh = (i % 2 == 0) ? Ybh : X0h;
        u16* outl = (i % 2 == 0) ? Ybl : X0l;
        if (i == 0) {
            gemm_plain<128,128,256,true,false><<<dim3(192,1), 256, 0, stream>>>(
                Wh+of1, Wl+of1, 128, Abh, Abl, 128,
                Wh+osc, Wl+osc, 256, X0h, X0l, 256,
                nullptr, nullptr, outh, outl, 128, PmCur);
        } else {
            gemm_plain<128,128,128,true,true><<<dim3(192,1), 256, 0, stream>>>(
                Wh+of1, Wl+of1, 128, Abh, Abl, 128,
                Wh+osc, Wl+osc, 256, Yph, Ypl, 128,
                blk_sc + (size_t)i*32768, PmPrev, outh, outl, 128, PmCur);
        }
        Yph = outh; Ypl = outl;
    }

    final_head_kernel<<<BB, 128, 0, stream>>>(PmBuf[0], w_actc_dir, w_fc_c, out);
}